// Round 1
// baseline (602.911 us; speedup 1.0000x reference)
//
#include <hip/hip_runtime.h>
#include <math.h>

#define D_ 96
#define H_ 128
#define W_ 128
#define NCH 64            // B*C = 2*32
#define CHUNKS 24         // 96 d-slices / 4 per chunk
#define SLICES_PER_CHUNK 4
#define F4_PER_CHUNK (SLICES_PER_CHUNK * H_ * W_ / 4)   // 16384
#define F4_PER_SLICE (H_ * W_ / 4)                      // 4096

// Kernel 1: per-(channel, d-chunk) partial reduction of {mass, sum(v*x), sum(v*y), sum(v*z)}.
// Memory-bound streaming pass over the whole 402.6 MB input with float4 loads.
__global__ __launch_bounds__(256) void tooth_reduce_kernel(
        const float* __restrict__ seg, float* __restrict__ partials) {
    const int channel = blockIdx.y;   // b*32 + c
    const int chunk   = blockIdx.x;   // which group of 4 d-slices
    const int tid     = threadIdx.x;

    const float4* __restrict__ p = reinterpret_cast<const float4*>(seg)
        + (size_t)channel * (D_ * H_ * W_ / 4)
        + (size_t)chunk * F4_PER_CHUNK;
    const float dbase = (float)(chunk * SLICES_PER_CHUNK);

    float m = 0.f, wx = 0.f, wy = 0.f, wz = 0.f;
    for (int i = tid; i < F4_PER_CHUNK; i += 256) {
        float4 v = p[i];
        int slice = i >> 12;          // / 4096
        int rem   = i & 4095;
        int h     = rem >> 5;         // / 32 (32 float4 per 128-wide row)
        int w4    = rem & 31;
        float s  = (v.x + v.y) + (v.z + v.w);
        float wf = (float)(w4 << 2);
        m  += s;
        wx += s * wf + (v.y + 2.f * v.z + 3.f * v.w);
        wy += s * (float)h;
        wz += s * (dbase + (float)slice);
    }

    // wave64 shuffle reduction
    for (int off = 32; off > 0; off >>= 1) {
        m  += __shfl_down(m,  off, 64);
        wx += __shfl_down(wx, off, 64);
        wy += __shfl_down(wy, off, 64);
        wz += __shfl_down(wz, off, 64);
    }
    __shared__ float red[4][4];
    const int wave = tid >> 6;
    if ((tid & 63) == 0) {
        red[wave][0] = m; red[wave][1] = wx; red[wave][2] = wy; red[wave][3] = wz;
    }
    __syncthreads();
    if (tid == 0) {
        float M  = (red[0][0] + red[1][0]) + (red[2][0] + red[3][0]);
        float WX = (red[0][1] + red[1][1]) + (red[2][1] + red[3][1]);
        float WY = (red[0][2] + red[1][2]) + (red[2][2] + red[3][2]);
        float WZ = (red[0][3] + red[1][3]) + (red[2][3] + red[3][3]);
        float* o = partials + ((size_t)channel * CHUNKS + chunk) * 4;
        o[0] = M; o[1] = WX; o[2] = WY; o[3] = WZ;
    }
}

// Kernel 2: tiny epilogue. 64 threads finish the channel sums (double), thread 0
// computes all four losses in double (variance is two-pass — f32 E[x^2]-E[x]^2
// would be catastrophic at volume ~ 7.9e5) and writes the 5 float outputs.
__global__ void tooth_loss_kernel(const float* __restrict__ partials,
                                  float* __restrict__ out) {
    __shared__ double cx[NCH], cy[NCH], cz[NCH], vol[NCH];
    const int c = threadIdx.x;
    if (c < NCH) {
        double S = 0, WX = 0, WY = 0, WZ = 0;
        const float* p = partials + (size_t)c * CHUNKS * 4;
        for (int j = 0; j < CHUNKS; j++) {
            S  += p[j * 4 + 0];
            WX += p[j * 4 + 1];
            WY += p[j * 4 + 2];
            WZ += p[j * 4 + 3];
        }
        vol[c] = S;
        double safe = (S > 0.0) ? S : 1.0;
        double ccx = WX / safe / (double)W_;
        double ccy = WY / safe / (double)H_;
        double ccz = WZ / safe / (double)D_;
        if (!(S > 0.0)) { ccx = 0.0; ccy = 0.0; ccz = 0.0; }
        cx[c] = ccx; cy[c] = ccy; cz[c] = ccz;
    }
    __syncthreads();
    if (c != 0) return;

    // expected positions
    double ex[32], ey[32], ez[32];
    for (int i = 0; i < 16; i++) {
        double a = -M_PI / 2.0 + (double)i * (M_PI / 15.0);
        ex[i] = 0.6 * cos(a); ey[i] = 0.6 * sin(a); ez[i] = 0.7;
    }
    for (int i = 0; i < 16; i++) {
        double a = M_PI / 2.0 - (double)i * (M_PI / 15.0);
        ex[16 + i] = 0.55 * cos(a); ey[16 + i] = 0.55 * sin(a); ez[16 + i] = 0.3;
    }

    // landmark = mean over (B=2, 32, 3) of (centers - expected)^2
    double lm = 0.0;
    for (int b = 0; b < 2; b++)
        for (int t = 0; t < 32; t++) {
            int id = b * 32 + t;
            double dx = cx[id] - ex[t], dy = cy[id] - ey[t], dz = cz[id] - ez[t];
            lm += dx * dx + dy * dy + dz * dz;
        }
    lm /= 192.0;

    // spatial: adjacent relu(dist-0.1) + opposing xy-MSE + opposing z hinge
    double spatial = 0.0;
    {
        double acc = 0.0;
        for (int half = 0; half < 2; half++) {
            int base = half * 16;
            for (int i = 0; i < 15; i++) {
                if (i == 7) continue;    // skip (8,9)/(24,25) 1-indexed gaps
                int t1 = base + i, t2 = base + i + 1;
                for (int b = 0; b < 2; b++) {
                    int i1 = b * 32 + t1, i2 = b * 32 + t2;
                    double dx = cx[i1] - cx[i2], dy = cy[i1] - cy[i2], dz = cz[i1] - cz[i2];
                    double dist = sqrt(dx * dx + dy * dy + dz * dz);
                    double r = dist - 0.1;
                    acc += (r > 0.0) ? r : 0.0;
                }
            }
        }
        spatial += acc / 2.0;     // mean over batch
    }
    {
        double xyacc = 0.0, zacc = 0.0;
        for (int half = 0; half < 2; half++) {
            for (int i = 0; i < 8; i++) {
                int t1 = half * 16 + i, t2 = half * 16 + 15 - i;   // opposing pairs
                for (int b = 0; b < 2; b++) {
                    int i1 = b * 32 + t1, i2 = b * 32 + t2;
                    double dx = cx[i1] - cx[i2], dy = cy[i1] - cy[i2];
                    double dz = cz[i1] - cz[i2];
                    xyacc += dx * dx + dy * dy;
                    double r = 0.3 - fabs(dz);
                    zacc += (r > 0.0) ? r : 0.0;
                }
            }
        }
        spatial += xyacc / 4.0;   // mean over (B, 2 dims)
        spatial += zacc / 2.0;    // mean over batch
    }

    // symmetry: yz-MSE + (x1+x2)^2, same pair set
    double symmetry = 0.0;
    {
        double yzacc = 0.0, xacc = 0.0;
        for (int half = 0; half < 2; half++) {
            for (int i = 0; i < 8; i++) {
                int t1 = half * 16 + i, t2 = half * 16 + 15 - i;
                for (int b = 0; b < 2; b++) {
                    int i1 = b * 32 + t1, i2 = b * 32 + t2;
                    double dy = cy[i1] - cy[i2], dz = cz[i1] - cz[i2];
                    double sx = cx[i1] + cx[i2];
                    yzacc += dy * dy + dz * dz;
                    xacc  += sx * sx;
                }
            }
        }
        symmetry = yzacc / 4.0 + xacc / 2.0;
    }

    // anatomy: sum over tooth-type groups of mean-over-batch sample variance (ddof=1)
    const int g0[8]  = {6, 7, 8, 9, 22, 23, 24, 25};
    const int g1[4]  = {5, 10, 21, 26};
    const int g2[8]  = {3, 4, 11, 12, 19, 20, 27, 28};
    const int g3[12] = {0, 1, 2, 13, 14, 15, 16, 17, 18, 29, 30, 31};
    double anatomy = 0.0;
    {
        const int* groups[4] = {g0, g1, g2, g3};
        const int  gn[4]     = {8, 4, 8, 12};
        for (int g = 0; g < 4; g++) {
            const int* idx = groups[g];
            int n = gn[g];
            double acc = 0.0;
            for (int b = 0; b < 2; b++) {
                double mean = 0.0;
                for (int k = 0; k < n; k++) mean += vol[b * 32 + idx[k]];
                mean /= (double)n;
                double ssd = 0.0;
                for (int k = 0; k < n; k++) {
                    double d = vol[b * 32 + idx[k]] - mean;
                    ssd += d * d;
                }
                acc += ssd / (double)(n - 1);
            }
            anatomy += acc / 2.0;  // mean over batch
        }
    }

    double L  = lm       * 10.0;
    double Sp = spatial  *  5.0;
    double Sy = symmetry *  3.0;
    double An = anatomy  *  7.0;
    out[0] = (float)L;
    out[1] = (float)Sp;
    out[2] = (float)Sy;
    out[3] = (float)An;
    out[4] = (float)(L + Sp + Sy + An);
}

extern "C" void kernel_launch(void* const* d_in, const int* in_sizes, int n_in,
                              void* d_out, int out_size, void* d_ws, size_t ws_size,
                              hipStream_t stream) {
    const float* seg = (const float*)d_in[0];
    float* partials  = (float*)d_ws;       // 64 channels * 24 chunks * 4 floats = 24 KB
    float* out       = (float*)d_out;

    dim3 grid(CHUNKS, NCH);                // 24 x 64 = 1536 blocks, 6 blocks/CU
    tooth_reduce_kernel<<<grid, 256, 0, stream>>>(seg, partials);
    tooth_loss_kernel<<<1, 64, 0, stream>>>(partials, out);
}

// Round 2
// 582.172 us; speedup vs baseline: 1.0356x; 1.0356x over previous
//
#include <hip/hip_runtime.h>
#include <math.h>

#define D_ 96
#define H_ 128
#define W_ 128
#define NCH 64            // B*C = 2*32
#define CHUNKS 24         // 96 d-slices / 4 per chunk
#define SLICES_PER_CHUNK 4
#define F4_PER_CHUNK (SLICES_PER_CHUNK * H_ * W_ / 4)   // 16384

// Kernel 1: per-(channel, d-chunk) partial reduction of {mass, sum(v*x), sum(v*y), sum(v*z)}.
// Streaming pass over 402.6 MB. Key trick: with stride-256 float4 iteration,
//   w4 = i & 31        -> per-thread CONSTANT  (256 % 32 == 0)
//   h  = h0 + 8*(j&15) -> affine in j
//   slice = j >> 4     -> uniform per 16-iteration group
// so all coordinate weights hoist out of the hot loop; body = 1 load + ~9 VALU.
__global__ __launch_bounds__(256) void tooth_reduce_kernel(
        const float* __restrict__ seg, float* __restrict__ partials) {
    const int channel = blockIdx.y;   // b*32 + c
    const int chunk   = blockIdx.x;   // group of 4 d-slices
    const int tid     = threadIdx.x;

    const float4* __restrict__ p = reinterpret_cast<const float4*>(seg)
        + (size_t)channel * (D_ * H_ * W_ / 4)
        + (size_t)chunk * F4_PER_CHUNK;

    float m = 0.f, corr = 0.f, tj = 0.f, tk = 0.f;
    for (int jo = 0; jo < 4; jo++) {            // slice index within chunk
        float sk = 0.f;
        #pragma unroll
        for (int ji = 0; ji < 16; ji++) {       // 16 loads in flight
            float4 v = p[tid + ((jo * 16 + ji) << 8)];
            float s = (v.x + v.y) + (v.z + v.w);
            m    += s;
            corr += v.y + 2.f * v.z + 3.f * v.w;     // intra-float4 x offsets
            tj   += s * (float)ji;                   // h-weight (affine part)
            sk   += s;
        }
        tk += sk * (float)jo;                        // slice (z) weight
    }
    const float wf = (float)((tid & 31) << 2);   // per-thread x base
    const float h0 = (float)(tid >> 5);          // per-thread h base
    const float dbase = (float)(chunk * SLICES_PER_CHUNK);
    float wx = fmaf(wf, m, corr);
    float wy = fmaf(h0, m, 8.f * tj);
    float wz = fmaf(dbase, m, tk);

    // wave64 shuffle reduction
    for (int off = 32; off > 0; off >>= 1) {
        m  += __shfl_down(m,  off, 64);
        wx += __shfl_down(wx, off, 64);
        wy += __shfl_down(wy, off, 64);
        wz += __shfl_down(wz, off, 64);
    }
    __shared__ float red[4][4];
    const int wave = tid >> 6;
    if ((tid & 63) == 0) {
        red[wave][0] = m; red[wave][1] = wx; red[wave][2] = wy; red[wave][3] = wz;
    }
    __syncthreads();
    if (tid == 0) {
        float M  = (red[0][0] + red[1][0]) + (red[2][0] + red[3][0]);
        float WX = (red[0][1] + red[1][1]) + (red[2][1] + red[3][1]);
        float WY = (red[0][2] + red[1][2]) + (red[2][2] + red[3][2]);
        float WZ = (red[0][3] + red[1][3]) + (red[2][3] + red[3][3]);
        float* o = partials + ((size_t)channel * CHUNKS + chunk) * 4;
        o[0] = M; o[1] = WX; o[2] = WY; o[3] = WZ;
    }
}

// Kernel 2: tiny epilogue in double (variance must be two-pass at volume ~8e5).
// Expected-position trig hard-coded (values of sin/cos(i*pi/15)) — no f64
// transcendental software sequences on the single hot thread.
__constant__ double TRIG_S[16] = {
    0.0, 0.20791169081775934, 0.40673664307580021, 0.58778525229247314,
    0.74314482547739424, 0.86602540378443865, 0.95105651629515353,
    0.99452189536827329, 0.99452189536827329, 0.95105651629515353,
    0.86602540378443865, 0.74314482547739424, 0.58778525229247314,
    0.40673664307580021, 0.20791169081775934, 0.0 };
__constant__ double TRIG_C[16] = {
    1.0, 0.9781476007338057, 0.91354545764260087, 0.80901699437494745,
    0.66913060635885824, 0.5, 0.30901699437494742, 0.10452846326765347,
    -0.10452846326765333, -0.30901699437494742, -0.5, -0.66913060635885824,
    -0.80901699437494745, -0.91354545764260087, -0.9781476007338057, -1.0 };

__global__ void tooth_loss_kernel(const float* __restrict__ partials,
                                  float* __restrict__ out) {
    __shared__ double cx[NCH], cy[NCH], cz[NCH], vol[NCH];
    const int c = threadIdx.x;
    if (c < NCH) {
        double S = 0, WX = 0, WY = 0, WZ = 0;
        const float* p = partials + (size_t)c * CHUNKS * 4;
        for (int j = 0; j < CHUNKS; j++) {
            S  += p[j * 4 + 0];
            WX += p[j * 4 + 1];
            WY += p[j * 4 + 2];
            WZ += p[j * 4 + 3];
        }
        vol[c] = S;
        double safe = (S > 0.0) ? S : 1.0;
        double ccx = WX / safe / (double)W_;
        double ccy = WY / safe / (double)H_;
        double ccz = WZ / safe / (double)D_;
        if (!(S > 0.0)) { ccx = 0.0; ccy = 0.0; ccz = 0.0; }
        cx[c] = ccx; cy[c] = ccy; cz[c] = ccz;
    }
    __syncthreads();
    if (c != 0) return;

    // expected positions from trig table
    double ex[32], ey[32], ez[32];
    for (int i = 0; i < 16; i++) {
        ex[i] = 0.6 * TRIG_S[i];  ey[i] = -0.6 * TRIG_C[i];  ez[i] = 0.7;   // upper
        ex[16 + i] = 0.55 * TRIG_S[i]; ey[16 + i] = 0.55 * TRIG_C[i]; ez[16 + i] = 0.3; // lower
    }

    // landmark = mean over (B=2, 32, 3)
    double lm = 0.0;
    for (int b = 0; b < 2; b++)
        for (int t = 0; t < 32; t++) {
            int id = b * 32 + t;
            double dx = cx[id] - ex[t], dy = cy[id] - ey[t], dz = cz[id] - ez[t];
            lm += dx * dx + dy * dy + dz * dz;
        }
    lm /= 192.0;

    // spatial: adjacent hinge + opposing xy-MSE + opposing z hinge
    double spatial = 0.0;
    {
        double acc = 0.0;
        for (int half = 0; half < 2; half++) {
            int base = half * 16;
            for (int i = 0; i < 15; i++) {
                if (i == 7) continue;
                int t1 = base + i, t2 = base + i + 1;
                for (int b = 0; b < 2; b++) {
                    int i1 = b * 32 + t1, i2 = b * 32 + t2;
                    double dx = cx[i1] - cx[i2], dy = cy[i1] - cy[i2], dz = cz[i1] - cz[i2];
                    double dist = sqrt(dx * dx + dy * dy + dz * dz);
                    double r = dist - 0.1;
                    acc += (r > 0.0) ? r : 0.0;
                }
            }
        }
        spatial += acc / 2.0;
    }
    {
        double xyacc = 0.0, zacc = 0.0;
        for (int half = 0; half < 2; half++) {
            for (int i = 0; i < 8; i++) {
                int t1 = half * 16 + i, t2 = half * 16 + 15 - i;
                for (int b = 0; b < 2; b++) {
                    int i1 = b * 32 + t1, i2 = b * 32 + t2;
                    double dx = cx[i1] - cx[i2], dy = cy[i1] - cy[i2];
                    double dz = cz[i1] - cz[i2];
                    xyacc += dx * dx + dy * dy;
                    double r = 0.3 - fabs(dz);
                    zacc += (r > 0.0) ? r : 0.0;
                }
            }
        }
        spatial += xyacc / 4.0;
        spatial += zacc / 2.0;
    }

    // symmetry: yz-MSE + (x1+x2)^2
    double symmetry = 0.0;
    {
        double yzacc = 0.0, xacc = 0.0;
        for (int half = 0; half < 2; half++) {
            for (int i = 0; i < 8; i++) {
                int t1 = half * 16 + i, t2 = half * 16 + 15 - i;
                for (int b = 0; b < 2; b++) {
                    int i1 = b * 32 + t1, i2 = b * 32 + t2;
                    double dy = cy[i1] - cy[i2], dz = cz[i1] - cz[i2];
                    double sx = cx[i1] + cx[i2];
                    yzacc += dy * dy + dz * dz;
                    xacc  += sx * sx;
                }
            }
        }
        symmetry = yzacc / 4.0 + xacc / 2.0;
    }

    // anatomy: per tooth-type group, mean-over-batch sample variance (ddof=1)
    const int g0[8]  = {6, 7, 8, 9, 22, 23, 24, 25};
    const int g1[4]  = {5, 10, 21, 26};
    const int g2[8]  = {3, 4, 11, 12, 19, 20, 27, 28};
    const int g3[12] = {0, 1, 2, 13, 14, 15, 16, 17, 18, 29, 30, 31};
    double anatomy = 0.0;
    {
        const int* groups[4] = {g0, g1, g2, g3};
        const int  gn[4]     = {8, 4, 8, 12};
        for (int g = 0; g < 4; g++) {
            const int* idx = groups[g];
            int n = gn[g];
            double acc = 0.0;
            for (int b = 0; b < 2; b++) {
                double mean = 0.0;
                for (int k = 0; k < n; k++) mean += vol[b * 32 + idx[k]];
                mean /= (double)n;
                double ssd = 0.0;
                for (int k = 0; k < n; k++) {
                    double d = vol[b * 32 + idx[k]] - mean;
                    ssd += d * d;
                }
                acc += ssd / (double)(n - 1);
            }
            anatomy += acc / 2.0;
        }
    }

    double L  = lm       * 10.0;
    double Sp = spatial  *  5.0;
    double Sy = symmetry *  3.0;
    double An = anatomy  *  7.0;
    out[0] = (float)L;
    out[1] = (float)Sp;
    out[2] = (float)Sy;
    out[3] = (float)An;
    out[4] = (float)(L + Sp + Sy + An);
}

extern "C" void kernel_launch(void* const* d_in, const int* in_sizes, int n_in,
                              void* d_out, int out_size, void* d_ws, size_t ws_size,
                              hipStream_t stream) {
    const float* seg = (const float*)d_in[0];
    float* partials  = (float*)d_ws;       // 64 * 24 * 4 floats = 24 KB
    float* out       = (float*)d_out;

    dim3 grid(CHUNKS, NCH);                // 1536 blocks = 6 blocks/CU, zero tail
    tooth_reduce_kernel<<<grid, 256, 0, stream>>>(seg, partials);
    tooth_loss_kernel<<<1, 64, 0, stream>>>(partials, out);
}

// Round 4
// 549.720 us; speedup vs baseline: 1.0968x; 1.0590x over previous
//
#include <hip/hip_runtime.h>
#include <math.h>

#define D_ 96
#define H_ 128
#define W_ 128
#define NCH 64            // B*C = 2*32
#define CHUNKS 24         // 96 d-slices / 4 per chunk
#define SLICES_PER_CHUNK 4
#define F4_PER_CHUNK (SLICES_PER_CHUNK * H_ * W_ / 4)   // 16384

// clang native vector — __builtin_nontemporal_load requires scalar/native-vector,
// not HIP_vector_type<float,4>.
typedef float floatx4 __attribute__((ext_vector_type(4)));

// Kernel 1: per-(channel, d-chunk) partial reduction of {mass, sum(v*x), sum(v*y), sum(v*z)}.
// Streaming pass over 402.6 MB with NONTEMPORAL float4 loads (no L2/L3 allocate:
// avoids dirty-eviction writeback storms from the harness's 1.5 GiB poison fill
// + 402 MB input restore that immediately precede us in the timed window).
// Coordinate weights hoist out of the hot loop (stride-256 float4 iteration):
//   w4 = i & 31        -> per-thread CONSTANT
//   h  = h0 + 8*ji     -> affine in inner index
//   slice = jo         -> uniform per 16-iteration group
__global__ __launch_bounds__(256) void tooth_reduce_kernel(
        const float* __restrict__ seg, float* __restrict__ partials) {
    const int channel = blockIdx.y;   // b*32 + c
    const int chunk   = blockIdx.x;   // group of 4 d-slices
    const int tid     = threadIdx.x;

    const floatx4* __restrict__ p = reinterpret_cast<const floatx4*>(seg)
        + (size_t)channel * (D_ * H_ * W_ / 4)
        + (size_t)chunk * F4_PER_CHUNK;

    float m = 0.f, corr = 0.f, tj = 0.f, tk = 0.f;
    for (int jo = 0; jo < 4; jo++) {            // slice index within chunk
        float sk = 0.f;
        #pragma unroll
        for (int ji = 0; ji < 16; ji++) {       // 16 loads in flight
            floatx4 v = __builtin_nontemporal_load(&p[tid + ((jo * 16 + ji) << 8)]);
            float s = (v.x + v.y) + (v.z + v.w);
            m    += s;
            corr += v.y + 2.f * v.z + 3.f * v.w;     // intra-float4 x offsets
            tj   += s * (float)ji;                   // h-weight (affine part)
            sk   += s;
        }
        tk += sk * (float)jo;                        // slice (z) weight
    }
    const float wf = (float)((tid & 31) << 2);   // per-thread x base
    const float h0 = (float)(tid >> 5);          // per-thread h base
    const float dbase = (float)(chunk * SLICES_PER_CHUNK);
    float wx = fmaf(wf, m, corr);
    float wy = fmaf(h0, m, 8.f * tj);
    float wz = fmaf(dbase, m, tk);

    // wave64 shuffle reduction
    for (int off = 32; off > 0; off >>= 1) {
        m  += __shfl_down(m,  off, 64);
        wx += __shfl_down(wx, off, 64);
        wy += __shfl_down(wy, off, 64);
        wz += __shfl_down(wz, off, 64);
    }
    __shared__ float red[4][4];
    const int wave = tid >> 6;
    if ((tid & 63) == 0) {
        red[wave][0] = m; red[wave][1] = wx; red[wave][2] = wy; red[wave][3] = wz;
    }
    __syncthreads();
    if (tid == 0) {
        float M  = (red[0][0] + red[1][0]) + (red[2][0] + red[3][0]);
        float WX = (red[0][1] + red[1][1]) + (red[2][1] + red[3][1]);
        float WY = (red[0][2] + red[1][2]) + (red[2][2] + red[3][2]);
        float WZ = (red[0][3] + red[1][3]) + (red[2][3] + red[3][3]);
        float* o = partials + ((size_t)channel * CHUNKS + chunk) * 4;
        o[0] = M; o[1] = WX; o[2] = WY; o[3] = WZ;
    }
}

// Kernel 2: tiny epilogue in double (variance must be two-pass at volume ~8e5).
// Expected-position trig hard-coded — no f64 transcendental software sequences.
__constant__ double TRIG_S[16] = {
    0.0, 0.20791169081775934, 0.40673664307580021, 0.58778525229247314,
    0.74314482547739424, 0.86602540378443865, 0.95105651629515353,
    0.99452189536827329, 0.99452189536827329, 0.95105651629515353,
    0.86602540378443865, 0.74314482547739424, 0.58778525229247314,
    0.40673664307580021, 0.20791169081775934, 0.0 };
__constant__ double TRIG_C[16] = {
    1.0, 0.9781476007338057, 0.91354545764260087, 0.80901699437494745,
    0.66913060635885824, 0.5, 0.30901699437494742, 0.10452846326765347,
    -0.10452846326765333, -0.30901699437494742, -0.5, -0.66913060635885824,
    -0.80901699437494745, -0.91354545764260087, -0.9781476007338057, -1.0 };

__global__ void tooth_loss_kernel(const float* __restrict__ partials,
                                  float* __restrict__ out) {
    __shared__ double cx[NCH], cy[NCH], cz[NCH], vol[NCH];
    const int c = threadIdx.x;
    if (c < NCH) {
        double S = 0, WX = 0, WY = 0, WZ = 0;
        const float* p = partials + (size_t)c * CHUNKS * 4;
        for (int j = 0; j < CHUNKS; j++) {
            S  += p[j * 4 + 0];
            WX += p[j * 4 + 1];
            WY += p[j * 4 + 2];
            WZ += p[j * 4 + 3];
        }
        vol[c] = S;
        double safe = (S > 0.0) ? S : 1.0;
        double ccx = WX / safe / (double)W_;
        double ccy = WY / safe / (double)H_;
        double ccz = WZ / safe / (double)D_;
        if (!(S > 0.0)) { ccx = 0.0; ccy = 0.0; ccz = 0.0; }
        cx[c] = ccx; cy[c] = ccy; cz[c] = ccz;
    }
    __syncthreads();
    if (c != 0) return;

    // expected positions from trig table
    double ex[32], ey[32], ez[32];
    for (int i = 0; i < 16; i++) {
        ex[i] = 0.6 * TRIG_S[i];  ey[i] = -0.6 * TRIG_C[i];  ez[i] = 0.7;   // upper
        ex[16 + i] = 0.55 * TRIG_S[i]; ey[16 + i] = 0.55 * TRIG_C[i]; ez[16 + i] = 0.3; // lower
    }

    // landmark = mean over (B=2, 32, 3)
    double lm = 0.0;
    for (int b = 0; b < 2; b++)
        for (int t = 0; t < 32; t++) {
            int id = b * 32 + t;
            double dx = cx[id] - ex[t], dy = cy[id] - ey[t], dz = cz[id] - ez[t];
            lm += dx * dx + dy * dy + dz * dz;
        }
    lm /= 192.0;

    // spatial: adjacent hinge + opposing xy-MSE + opposing z hinge
    double spatial = 0.0;
    {
        double acc = 0.0;
        for (int half = 0; half < 2; half++) {
            int base = half * 16;
            for (int i = 0; i < 15; i++) {
                if (i == 7) continue;
                int t1 = base + i, t2 = base + i + 1;
                for (int b = 0; b < 2; b++) {
                    int i1 = b * 32 + t1, i2 = b * 32 + t2;
                    double dx = cx[i1] - cx[i2], dy = cy[i1] - cy[i2], dz = cz[i1] - cz[i2];
                    double dist = sqrt(dx * dx + dy * dy + dz * dz);
                    double r = dist - 0.1;
                    acc += (r > 0.0) ? r : 0.0;
                }
            }
        }
        spatial += acc / 2.0;
    }
    {
        double xyacc = 0.0, zacc = 0.0;
        for (int half = 0; half < 2; half++) {
            for (int i = 0; i < 8; i++) {
                int t1 = half * 16 + i, t2 = half * 16 + 15 - i;
                for (int b = 0; b < 2; b++) {
                    int i1 = b * 32 + t1, i2 = b * 32 + t2;
                    double dx = cx[i1] - cx[i2], dy = cy[i1] - cy[i2];
                    double dz = cz[i1] - cz[i2];
                    xyacc += dx * dx + dy * dy;
                    double r = 0.3 - fabs(dz);
                    zacc += (r > 0.0) ? r : 0.0;
                }
            }
        }
        spatial += xyacc / 4.0;
        spatial += zacc / 2.0;
    }

    // symmetry: yz-MSE + (x1+x2)^2
    double symmetry = 0.0;
    {
        double yzacc = 0.0, xacc = 0.0;
        for (int half = 0; half < 2; half++) {
            for (int i = 0; i < 8; i++) {
                int t1 = half * 16 + i, t2 = half * 16 + 15 - i;
                for (int b = 0; b < 2; b++) {
                    int i1 = b * 32 + t1, i2 = b * 32 + t2;
                    double dy = cy[i1] - cy[i2], dz = cz[i1] - cz[i2];
                    double sx = cx[i1] + cx[i2];
                    yzacc += dy * dy + dz * dz;
                    xacc  += sx * sx;
                }
            }
        }
        symmetry = yzacc / 4.0 + xacc / 2.0;
    }

    // anatomy: per tooth-type group, mean-over-batch sample variance (ddof=1)
    const int g0[8]  = {6, 7, 8, 9, 22, 23, 24, 25};
    const int g1[4]  = {5, 10, 21, 26};
    const int g2[8]  = {3, 4, 11, 12, 19, 20, 27, 28};
    const int g3[12] = {0, 1, 2, 13, 14, 15, 16, 17, 18, 29, 30, 31};
    double anatomy = 0.0;
    {
        const int* groups[4] = {g0, g1, g2, g3};
        const int  gn[4]     = {8, 4, 8, 12};
        for (int g = 0; g < 4; g++) {
            const int* idx = groups[g];
            int n = gn[g];
            double acc = 0.0;
            for (int b = 0; b < 2; b++) {
                double mean = 0.0;
                for (int k = 0; k < n; k++) mean += vol[b * 32 + idx[k]];
                mean /= (double)n;
                double ssd = 0.0;
                for (int k = 0; k < n; k++) {
                    double d = vol[b * 32 + idx[k]] - mean;
                    ssd += d * d;
                }
                acc += ssd / (double)(n - 1);
            }
            anatomy += acc / 2.0;
        }
    }

    double L  = lm       * 10.0;
    double Sp = spatial  *  5.0;
    double Sy = symmetry *  3.0;
    double An = anatomy  *  7.0;
    out[0] = (float)L;
    out[1] = (float)Sp;
    out[2] = (float)Sy;
    out[3] = (float)An;
    out[4] = (float)(L + Sp + Sy + An);
}

extern "C" void kernel_launch(void* const* d_in, const int* in_sizes, int n_in,
                              void* d_out, int out_size, void* d_ws, size_t ws_size,
                              hipStream_t stream) {
    const float* seg = (const float*)d_in[0];
    float* partials  = (float*)d_ws;       // 64 * 24 * 4 floats = 24 KB
    float* out       = (float*)d_out;

    dim3 grid(CHUNKS, NCH);                // 1536 blocks = 6 blocks/CU, zero tail
    tooth_reduce_kernel<<<grid, 256, 0, stream>>>(seg, partials);
    tooth_loss_kernel<<<1, 64, 0, stream>>>(partials, out);
}